// Round 8
// baseline (127.196 us; speedup 1.0000x reference)
//
#include <hip/hip_runtime.h>

#define BATCH 16384
#define DIM   512
#define NCLS  2048

typedef _Float16 half8 __attribute__((ext_vector_type(8)));
typedef float    floatx4 __attribute__((ext_vector_type(4)));

__device__ inline unsigned pack2bf(float a, float b) {
    unsigned ua = (__builtin_bit_cast(unsigned, a) + 0x8000u) >> 16;
    unsigned ub = (__builtin_bit_cast(unsigned, b) + 0x8000u) >> 16;
    return ua | (ub << 16);
}
__device__ inline float ubf_lo(unsigned u) { return __builtin_bit_cast(float, u << 16); }
__device__ inline float ubf_hi(unsigned u) { return __builtin_bit_cast(float, u & 0xffff0000u); }

// ---------------- pack centers into 16x16x32 MFMA B-fragment order ----------------
// Granule t = (n*16 + s)*64 + lane holds C[n*16 + (lane&15)][s*32 + (lane>>4)*8 .. +8]
// => a wave's B-fragment load is one contiguous 16B-aligned 1KB global_load_dwordx4.
// R7-verified layout.
__global__ __launch_bounds__(256) void pack_b(const float* __restrict__ C,
                                              _Float16* __restrict__ BP) {
    int t = blockIdx.x * 256 + threadIdx.x;   // [0, 128*16*64)
    int lane = t & 63, ns = t >> 6;
    int s = ns & 15, n = ns >> 4;
    int col = n * 16 + (lane & 15);
    int k   = s * 32 + (lane >> 4) * 8;
    const float4* src = reinterpret_cast<const float4*>(C + (size_t)col * DIM + k);
    float4 a = src[0], b = src[1];
    half8 h;
    h[0] = (_Float16)a.x; h[1] = (_Float16)a.y; h[2] = (_Float16)a.z; h[3] = (_Float16)a.w;
    h[4] = (_Float16)b.x; h[5] = (_Float16)b.y; h[6] = (_Float16)b.z; h[7] = (_Float16)b.w;
    *reinterpret_cast<half8*>(BP + (size_t)t * 8) = h;
}

// ---------------- 0.5 * ||c_k||^2, one wave per class ----------------
__global__ __launch_bounds__(64) void csq_kernel(const float* __restrict__ c,
                                                 float* __restrict__ hcsq) {
    int k = blockIdx.x, t = threadIdx.x;
    const float4* p = reinterpret_cast<const float4*>(c + (size_t)k * DIM);
    float s = 0.f;
    #pragma unroll
    for (int j = 0; j < 2; ++j) {
        float4 v = p[t + j * 64];
        s += v.x * v.x + v.y * v.y + v.z * v.z + v.w * v.w;
    }
    #pragma unroll
    for (int o = 32; o; o >>= 1) s += __shfl_xor(s, o);
    if (t == 0) hcsq[k] = 0.5f * s;
}

// ---------------- fused GEMM + softmax, M=64, online bf16 state ----------------
// grid 256 x 512 thr (8 waves). Block owns 64 rows x all 2048 cols, 8 chunks of 256.
// Wave: rw = wave&1 (rows rw*32..+32), cg = wave>>1 (cols cg*64 per chunk).
// Per chunk: 2rt x 4ct fragments of 16x16x32; B global->reg from packed BP (L2).
// Chunk and K-step order staggered by (bid>>3) so co-XCD blocks hit different L2
// lines (anti-hotspot). Exp state: ev = exp(l - mhat) packed bf16 (128 regs),
// mhat = per-(chunk,rt,row) fragment max, bf16 (32 regs). Final: M = max(mhat),
// scale = exp(mhat - M) <= 1, row sum >= e^-0.3 > 0 => nan impossible.
__global__ __launch_bounds__(512, 2) void fused_kernel(
    const float* __restrict__ X,       // [BATCH][DIM] fp32
    const _Float16* __restrict__ BP,   // packed B fragments (2 MB)
    const float* __restrict__ hcsq,    // [NCLS] 0.5*||c||^2
    float* __restrict__ O)             // [BATCH][NCLS]
{
    __shared__ __align__(16) _Float16 As[64 * 512];   // 64 KB, granule-swizzled
    __shared__ float redm[4][64];
    __shared__ float rsum[4][64];

    const int tid  = threadIdx.x;
    const int lane = tid & 63;
    const int wave = tid >> 6;
    const int rw   = wave & 1;      // row half
    const int cg   = wave >> 1;     // col group 0..3
    const int l4   = lane >> 4;
    const int r15  = lane & 15;
    const int rowB = blockIdx.x * 64;
    const int stgc = (blockIdx.x >> 3) & 7;     // chunk phase (varies within an XCD)
    const int stgs = (blockIdx.x >> 3) & 15;    // K-step phase

    // ---- stage A: 64 rows, fp32 -> fp16, 16B granules XOR-swizzled ----
    #pragma unroll
    for (int i = 0; i < 8; ++i) {
        int G = i * 512 + tid;              // 4096 granules = 64 rows x 64
        int row = G >> 6, g = G & 63;
        const float* src = X + (size_t)(rowB + row) * DIM + g * 8;
        float4 a = *reinterpret_cast<const float4*>(src);
        float4 b = *reinterpret_cast<const float4*>(src + 4);
        half8 h;
        h[0] = (_Float16)a.x; h[1] = (_Float16)a.y; h[2] = (_Float16)a.z; h[3] = (_Float16)a.w;
        h[4] = (_Float16)b.x; h[5] = (_Float16)b.y; h[6] = (_Float16)b.z; h[7] = (_Float16)b.w;
        *reinterpret_cast<half8*>(&As[(row * 64 + (g ^ (row & 7))) * 8]) = h;
    }
    __syncthreads();

    unsigned ev[8][2][4][2];    // packed bf16 exp pairs [c0][rt][ct][jpair]
    unsigned mh[8][2][2];       // packed bf16 mhat     [c0][rt][jpair]

    #pragma unroll
    for (int c0 = 0; c0 < 8; ++c0) {
        const int ch = (c0 + stgc) & 7;     // actual column chunk

        floatx4 acc[2][4];
        #pragma unroll
        for (int rt = 0; rt < 2; ++rt)
            #pragma unroll
            for (int ct = 0; ct < 4; ++ct)
                acc[rt][ct] = (floatx4){0.f, 0.f, 0.f, 0.f};

        float hc[4];
        #pragma unroll
        for (int ct = 0; ct < 4; ++ct)
            hc[ct] = hcsq[ch * 256 + cg * 64 + ct * 16 + r15];

        // n(ct) = ch*16 + cg*4 + ct; granule = (n*16 + s)*64 + lane
        const _Float16* bb = BP + ((size_t)(ch * 16 + cg * 4) * 1024 + lane) * 8;

        #pragma unroll 4
        for (int s0 = 0; s0 < 16; ++s0) {
            const int s = (s0 + stgs) & 15;
            half8 bf[4];
            #pragma unroll
            for (int ct = 0; ct < 4; ++ct)
                bf[ct] = *reinterpret_cast<const half8*>(
                    bb + (size_t)((ct * 16 + s) * 64) * 8);
            const int kg = s * 4 + l4;
            const int sw = kg ^ (r15 & 7);
            half8 af0 = *reinterpret_cast<const half8*>(
                &As[((rw * 32 + r15) * 64 + sw) * 8]);
            half8 af1 = *reinterpret_cast<const half8*>(
                &As[((rw * 32 + 16 + r15) * 64 + sw) * 8]);
            #pragma unroll
            for (int ct = 0; ct < 4; ++ct) {
                acc[0][ct] = __builtin_amdgcn_mfma_f32_16x16x32_f16(af0, bf[ct], acc[0][ct], 0, 0, 0);
                acc[1][ct] = __builtin_amdgcn_mfma_f32_16x16x32_f16(af1, bf[ct], acc[1][ct], 0, 0, 0);
            }
        }

        // chunk epilogue: logits, fragment-group max (over ct and 16 cols), ev
        #pragma unroll
        for (int rt = 0; rt < 2; ++rt) {
            float l[4][4];
            float mj[4] = {-1e30f, -1e30f, -1e30f, -1e30f};
            #pragma unroll
            for (int ct = 0; ct < 4; ++ct)
                #pragma unroll
                for (int j = 0; j < 4; ++j) {
                    l[ct][j] = acc[rt][ct][j] - hc[ct];
                    mj[j] = fmaxf(mj[j], l[ct][j]);
                }
            #pragma unroll
            for (int off = 8; off >= 1; off >>= 1)
                #pragma unroll
                for (int j = 0; j < 4; ++j)
                    mj[j] = fmaxf(mj[j], __shfl_xor(mj[j], off));
            // round mhat to bf16; use the ROUNDED value for subtraction (consistency)
            unsigned m01 = pack2bf(mj[0], mj[1]);
            unsigned m23 = pack2bf(mj[2], mj[3]);
            mh[c0][rt][0] = m01;
            mh[c0][rt][1] = m23;
            float mb[4] = {ubf_lo(m01), ubf_hi(m01), ubf_lo(m23), ubf_hi(m23)};
            #pragma unroll
            for (int ct = 0; ct < 4; ++ct) {
                float e0 = __expf(l[ct][0] - mb[0]);
                float e1 = __expf(l[ct][1] - mb[1]);
                float e2 = __expf(l[ct][2] - mb[2]);
                float e3 = __expf(l[ct][3] - mb[3]);
                ev[c0][rt][ct][0] = pack2bf(e0, e1);
                ev[c0][rt][ct][1] = pack2bf(e2, e3);
            }
        }
    }

    // ---- global row max M: local over chunks, then cross-wave (4 col-groups) ----
    float Ml[2][4];
    #pragma unroll
    for (int rt = 0; rt < 2; ++rt)
        #pragma unroll
        for (int j = 0; j < 4; ++j) Ml[rt][j] = -1e30f;
    #pragma unroll
    for (int c0 = 0; c0 < 8; ++c0)
        #pragma unroll
        for (int rt = 0; rt < 2; ++rt) {
            Ml[rt][0] = fmaxf(Ml[rt][0], ubf_lo(mh[c0][rt][0]));
            Ml[rt][1] = fmaxf(Ml[rt][1], ubf_hi(mh[c0][rt][0]));
            Ml[rt][2] = fmaxf(Ml[rt][2], ubf_lo(mh[c0][rt][1]));
            Ml[rt][3] = fmaxf(Ml[rt][3], ubf_hi(mh[c0][rt][1]));
        }
    if (r15 == 0) {
        #pragma unroll
        for (int rt = 0; rt < 2; ++rt)
            #pragma unroll
            for (int j = 0; j < 4; ++j)
                redm[cg][rw * 32 + rt * 16 + l4 * 4 + j] = Ml[rt][j];
    }
    __syncthreads();

    float M[2][4];
    #pragma unroll
    for (int rt = 0; rt < 2; ++rt)
        #pragma unroll
        for (int j = 0; j < 4; ++j) {
            const int r = rw * 32 + rt * 16 + l4 * 4 + j;
            M[rt][j] = fmaxf(fmaxf(redm[0][r], redm[1][r]),
                             fmaxf(redm[2][r], redm[3][r]));
        }

    // ---- row sums with per-chunk rescale ----
    float tot[2][4] = {{0.f, 0.f, 0.f, 0.f}, {0.f, 0.f, 0.f, 0.f}};
    #pragma unroll
    for (int c0 = 0; c0 < 8; ++c0)
        #pragma unroll
        for (int rt = 0; rt < 2; ++rt) {
            float sc[4];
            sc[0] = __expf(ubf_lo(mh[c0][rt][0]) - M[rt][0]);
            sc[1] = __expf(ubf_hi(mh[c0][rt][0]) - M[rt][1]);
            sc[2] = __expf(ubf_lo(mh[c0][rt][1]) - M[rt][2]);
            sc[3] = __expf(ubf_hi(mh[c0][rt][1]) - M[rt][3]);
            float es[4] = {0.f, 0.f, 0.f, 0.f};
            #pragma unroll
            for (int ct = 0; ct < 4; ++ct) {
                es[0] += ubf_lo(ev[c0][rt][ct][0]);
                es[1] += ubf_hi(ev[c0][rt][ct][0]);
                es[2] += ubf_lo(ev[c0][rt][ct][1]);
                es[3] += ubf_hi(ev[c0][rt][ct][1]);
            }
            #pragma unroll
            for (int j = 0; j < 4; ++j) tot[rt][j] += es[j] * sc[j];
        }
    #pragma unroll
    for (int off = 8; off >= 1; off >>= 1)
        #pragma unroll
        for (int rt = 0; rt < 2; ++rt)
            #pragma unroll
            for (int j = 0; j < 4; ++j)
                tot[rt][j] += __shfl_xor(tot[rt][j], off);
    if (r15 == 0) {
        #pragma unroll
        for (int rt = 0; rt < 2; ++rt)
            #pragma unroll
            for (int j = 0; j < 4; ++j)
                rsum[cg][rw * 32 + rt * 16 + l4 * 4 + j] = tot[rt][j];
    }
    __syncthreads();

    float inv[2][4];
    #pragma unroll
    for (int rt = 0; rt < 2; ++rt)
        #pragma unroll
        for (int j = 0; j < 4; ++j) {
            const int r = rw * 32 + rt * 16 + l4 * 4 + j;
            inv[rt][j] = 1.0f / (rsum[0][r] + rsum[1][r] + rsum[2][r] + rsum[3][r]);
        }

    // ---- single write: out = ev * exp(mhat - M) * inv ----
    #pragma unroll
    for (int c0 = 0; c0 < 8; ++c0) {
        const int ch = (c0 + stgc) & 7;
        #pragma unroll
        for (int rt = 0; rt < 2; ++rt) {
            float f[4];
            f[0] = __expf(ubf_lo(mh[c0][rt][0]) - M[rt][0]) * inv[rt][0];
            f[1] = __expf(ubf_hi(mh[c0][rt][0]) - M[rt][1]) * inv[rt][1];
            f[2] = __expf(ubf_lo(mh[c0][rt][1]) - M[rt][2]) * inv[rt][2];
            f[3] = __expf(ubf_hi(mh[c0][rt][1]) - M[rt][3]) * inv[rt][3];
            #pragma unroll
            for (int ct = 0; ct < 4; ++ct) {
                const int col = ch * 256 + cg * 64 + ct * 16 + r15;
                float* op = O + (size_t)(rowB + rw * 32 + rt * 16 + l4 * 4) * NCLS + col;
                op[0 * (size_t)NCLS] = ubf_lo(ev[c0][rt][ct][0]) * f[0];
                op[1 * (size_t)NCLS] = ubf_hi(ev[c0][rt][ct][0]) * f[1];
                op[2 * (size_t)NCLS] = ubf_lo(ev[c0][rt][ct][1]) * f[2];
                op[3 * (size_t)NCLS] = ubf_hi(ev[c0][rt][ct][1]) * f[3];
            }
        }
    }
}

extern "C" void kernel_launch(void* const* d_in, const int* in_sizes, int n_in,
                              void* d_out, int out_size, void* d_ws, size_t ws_size,
                              hipStream_t stream) {
    const float* x       = (const float*)d_in[0];
    const float* centers = (const float*)d_in[1];
    float* out = (float*)d_out;

    // ws layout: BP packed fp16 [128*16*64*8] (2 MB) | 0.5*csq [NCLS] (8 KB)
    _Float16* bp = (_Float16*)d_ws;
    float* hcsq  = (float*)(bp + (size_t)128 * 16 * 64 * 8);

    hipLaunchKernelGGL(pack_b, dim3(128 * 16 * 64 / 256), dim3(256), 0, stream, centers, bp);
    hipLaunchKernelGGL(csq_kernel, dim3(NCLS), dim3(64), 0, stream, centers, hcsq);
    hipLaunchKernelGGL(fused_kernel, dim3(BATCH / 64), dim3(512), 0, stream,
                       x, bp, hcsq, out);
}